// Round 4
// baseline (402.582 us; speedup 1.0000x reference)
//
#include <hip/hip_runtime.h>
#include <stdint.h>

#define IC   4096
#define BLK  256
#define VPT  4          // float4 chunks per thread
#define EPT  (VPT * 4)  // 16 elements/thread

// ---- fused f64+f32 block reduction (4 waves fixed), both broadcast ----
// Caller passes DISJOINT smd/smf slots per reduction -> no trailing barrier.
__device__ __forceinline__ void block_red_df(double& a, float& b, double* smd, float* smf) {
    #pragma unroll
    for (int off = 32; off; off >>= 1) {
        a += __shfl_xor(a, off);
        b += __shfl_xor(b, off);
    }
    const int wid = threadIdx.x >> 6;
    if ((threadIdx.x & 63) == 0) { smd[wid] = a; smf[wid] = b; }
    __syncthreads();
    a = smd[0] + smd[1] + smd[2] + smd[3];
    b = smf[0] + smf[1] + smf[2] + smf[3];
}

__device__ __forceinline__ double block_red_d(double a, double* smd) {
    #pragma unroll
    for (int off = 32; off; off >>= 1) a += __shfl_xor(a, off);
    const int wid = threadIdx.x >> 6;
    if ((threadIdx.x & 63) == 0) smd[wid] = a;
    __syncthreads();
    return smd[0] + smd[1] + smd[2] + smd[3];
}

__global__ __launch_bounds__(BLK) void binarize_kernel(
    const float* __restrict__ x,
    const uint8_t* __restrict__ mask,
    float* __restrict__ out)
{
    __shared__ double smd[12];
    __shared__ float  smf[8];
    __shared__ int    smi[4];
    const int row = blockIdx.x;
    const int tid = threadIdx.x;

    // ---- mask dtype detection (grid-uniform result), 1 barrier ----
    // int32 0/1 mask: every 32-bit word <= 1. byte bool mask: some word of
    // the first 256 has a nonzero upper byte w.p. ~1.
    int bad = (((const uint32_t*)mask)[tid] > 1u) ? 1 : 0;
    bad = __any(bad);
    if ((tid & 63) == 0) smi[tid >> 6] = bad;
    __syncthreads();
    const bool mask_is_i32 = ((smi[0] | smi[1] | smi[2] | smi[3]) == 0);

    const float* xr   = x + (size_t)row * IC;
    float*       orow = out + (size_t)row * IC;

    float xm[EPT];     // x * m  (exact: m is 0/1)
    float sgm[EPT];    // pass B: sign1*m in {-1,0,1}; pass D onward: (float)t2
    uint32_t mb = 0;   // per-thread 16-bit mask

    #pragma unroll
    for (int i = 0; i < VPT; ++i) {
        float4 v = ((const float4*)xr)[tid + i * BLK];
        xm[i*4+0] = v.x; xm[i*4+1] = v.y; xm[i*4+2] = v.z; xm[i*4+3] = v.w;
    }

    if (mask_is_i32) {
        const int4* mr = (const int4*)mask + (size_t)row * (IC / 4);
        #pragma unroll
        for (int i = 0; i < VPT; ++i) {
            int4 m4 = mr[tid + i * BLK];
            mb |= (uint32_t)(m4.x != 0) << (i*4+0);
            mb |= (uint32_t)(m4.y != 0) << (i*4+1);
            mb |= (uint32_t)(m4.z != 0) << (i*4+2);
            mb |= (uint32_t)(m4.w != 0) << (i*4+3);
        }
    } else {
        const uint32_t* mr = (const uint32_t*)(mask + (size_t)row * IC);
        #pragma unroll
        for (int i = 0; i < VPT; ++i) {
            uint32_t w = mr[tid + i * BLK];
            mb |= (uint32_t)((w & 0x000000ffu) != 0) << (i*4+0);
            mb |= (uint32_t)((w & 0x0000ff00u) != 0) << (i*4+1);
            mb |= (uint32_t)((w & 0x00ff0000u) != 0) << (i*4+2);
            mb |= (uint32_t)((w & 0xff000000u) != 0) << (i*4+3);
        }
    }

    #pragma unroll
    for (int j = 0; j < EPT; ++j)
        xm[j] = ((mb >> j) & 1u) ? xm[j] : 0.f;      // exact masking

    // ---- pass A: s = sum(x*m) [f64], c = count [popc, exact] ----
    double sA[2] = {0.0, 0.0};
    #pragma unroll
    for (int j = 0; j < EPT; ++j) sA[j & 1] += (double)xm[j];
    double s  = sA[0] + sA[1];
    float  cf = (float)__popc(mb);
    block_red_df(s, cf, smd + 0, smf + 0);

    const bool   has   = (cf > 0.f);
    const double c     = (double)cf;
    const double nmiss = (double)(4096.f - cf);      // # unmasked, exact
    const double inv   = 1.0 / fmax(c, 1.0);
    const double mean1 = has ? s * inv : 0.0;
    const float  mean1f = (float)mean1;

    // ---- pass B (f32 element math, f64 accumulate):
    // sa_all = sum|x*m - mean1f| over ALL lanes; unmasked lanes contribute
    // exactly |mean1f| (xm==0, f32 negation exact) -> corrected after.
    // Sign decision: near t==0 the f32 sub is Sterbenz-exact, so
    // sign(t_f32) == sign(x - mean1f) exactly; mean1f is within 1 ulp of
    // mean1 -> boundary within ~2e-11 of the verified-baseline boundary.
    double saB[2] = {0.0, 0.0};
    float  dB[2]  = {0.f, 0.f};
    #pragma unroll
    for (int j = 0; j < EPT; ++j) {
        const float t  = xm[j] - mean1f;
        const float sg = (t > 0.f) ? 1.f : ((t < 0.f) ? -1.f : 0.f);
        const float smv = ((mb >> j) & 1u) ? sg : 0.f;
        sgm[j] = smv;
        dB[j & 1]  += smv;
        saB[j & 1] += (double)fabsf(t);
    }
    double sa = saB[0] + saB[1];
    float  df = dB[0] + dB[1];
    block_red_df(sa, df, smd + 4, smf + 4);
    sa -= nmiss * (double)fabsf(mean1f);    // exact removal (36-bit product)

    const double scale1 = has ? sa * inv : 0.0;
    // pass C eliminated: sum((x-b1)*m) = s - scale1*d - mean1*c   (b1 = sign1*scale1 + mean1)
    const double mean2  = has ? (s - scale1 * (double)df - mean1 * c) * inv : 0.0;
    const double mean12 = mean1 + mean2;

    // ---- pass D (f64 element math — keeps the 2nd-order sign boundary
    // at the verified-baseline position): scale2 = mean |x - b1 - mean2|.
    // Unmasked lanes: sgm==0 -> t2 == -mean12 exactly -> corrected after.
    // Cache (float)t2 in sgm[] for the epilogue (sign preserved by f64->f32). ----
    double sbD[2] = {0.0, 0.0};
    #pragma unroll
    for (int j = 0; j < EPT; ++j) {
        const double t2 = (double)xm[j] - fma((double)sgm[j], scale1, mean12);
        sgm[j] = (float)t2;                 // reuse register array
        sbD[j & 1] += fabs(t2);
    }
    double sa2 = block_red_d(sbD[0] + sbD[1], smd + 8);
    sa2 -= nmiss * fabs(mean12);
    const double scale2 = has ? sa2 * inv : 0.0;
    const float  scale2f = (float)scale2;

    // ---- epilogue (f32): out = (b1 + sign2*scale2 + mean2) * m
    // b1 + mean2 == x - t2; sign2 from t2f is sign-exact. Value rounding
    // vs the f64 epilogue is ~few e-9 abs — same class as f64-vs-f32-ref. ----
    #pragma unroll
    for (int i = 0; i < VPT; ++i) {
        float r[4];
        #pragma unroll
        for (int k = 0; k < 4; ++k) {
            const int j = i * 4 + k;
            const float t2f = sgm[j];
            const float b1f = xm[j] - t2f;                 // b1 + mean2
            const float sg2 = (t2f > 0.f) ? 1.f : ((t2f < 0.f) ? -1.f : 0.f);
            const float o   = fmaf(sg2, scale2f, b1f);
            r[k] = ((mb >> j) & 1u) ? o : 0.f;             // unmasked -> exact 0
        }
        float4 o; o.x = r[0]; o.y = r[1]; o.z = r[2]; o.w = r[3];
        ((float4*)orow)[tid + i * BLK] = o;
    }
}

extern "C" void kernel_launch(void* const* d_in, const int* in_sizes, int n_in,
                              void* d_out, int out_size, void* d_ws, size_t ws_size,
                              hipStream_t stream) {
    const float*   x    = (const float*)d_in[0];
    const uint8_t* mask = (const uint8_t*)d_in[1];
    float*         out  = (float*)d_out;

    const int rows = in_sizes[0] / IC;   // 11008
    binarize_kernel<<<rows, BLK, 0, stream>>>(x, mask, out);
}